// Round 17
// baseline (114.858 us; speedup 1.0000x reference)
//
#include <hip/hip_runtime.h>
#include <hip/hip_fp16.h>
#include <math.h>

#define NPIX 15376   // 124*124

typedef _Float16 half8 __attribute__((ext_vector_type(8)));
typedef __fp16 fp16x2 __attribute__((ext_vector_type(2)));
typedef float f32x16 __attribute__((ext_vector_type(16)));

union Q2H { uint4 q; half8 h; };
union PK  { fp16x2 h; unsigned u; };
union UPK { uint2 q; _Float16 h[4]; };

// b = lin & 7 on every kernel: HW round-robins linear block id across the 8 XCDs, so
// all blocks of batch b share one XCD's L2 (x[b]=4MB, F2[b]=0.59MB resident) and L2
// content chains across kernels.

// ---------------- K1: fused pool + guide (heterogeneous blocks) ----------------------
__global__ __launch_bounds__(256) void k_poolguide(const float* __restrict__ x,
                                                   const float* __restrict__ wg,
                                                   const float* __restrict__ bg,
                                                   float* __restrict__ pooled,
                                                   unsigned char* __restrict__ rmap) {
  __shared__ float wgl[4608];   // guide: [ci][k][r]; pool uses only red[]
  __shared__ float red[4];
  int t = threadIdx.x;

  if (blockIdx.x < 512) {
    // ---------------- guide conv (f32) + argmax -> rmap, 1 px/thread ----------------
    // f32 accumulation order frozen (argmax exactness); unroll only issues loads
    // earlier, the fmaf sequence is unchanged.
    for (int i = t; i < 4608; i += 256) {
      int r = i / 576, rem = i % 576;      // rem = ci*9+k
      wgl[rem * 8 + r] = wg[i];
    }
    __syncthreads();
    int lin = blockIdx.x;             // 512
    int b = lin & 7;
    int tile = lin >> 3;              // 0..63
    int tx = tile & 7, ty = tile >> 3;
    int gx = tx * 16 + (t & 15);
    int gy = ty * 16 + (t >> 4);
    int xc = min(gx, 123);
    int yc = min(gy, 123);
    float a0[8];
    #pragma unroll
    for (int r = 0; r < 8; r++) a0[r] = bg[r];
    #pragma unroll 4
    for (int ci = 0; ci < 64; ci++) {
      const float* xp = x + ((size_t)(b * 64 + ci) * 126 + yc) * 126 + xc;
      const float4* wp4 = (const float4*)(wgl + ci * 72);
      #pragma unroll
      for (int k = 0; k < 9; k++) {
        float xv = xp[(k / 3) * 126 + (k % 3)];
        float4 wA = wp4[k * 2], wB = wp4[k * 2 + 1];
        a0[0] = fmaf(xv, wA.x, a0[0]); a0[1] = fmaf(xv, wA.y, a0[1]);
        a0[2] = fmaf(xv, wA.z, a0[2]); a0[3] = fmaf(xv, wA.w, a0[3]);
        a0[4] = fmaf(xv, wB.x, a0[4]); a0[5] = fmaf(xv, wB.y, a0[5]);
        a0[6] = fmaf(xv, wB.z, a0[6]); a0[7] = fmaf(xv, wB.w, a0[7]);
      }
    }
    if (gx < 124 && gy < 124) {
      int best = 0; float bv = a0[0];
      #pragma unroll
      for (int r = 1; r < 8; r++) if (a0[r] > bv) { bv = a0[r]; best = r; }
      rmap[b * NPIX + gy * 124 + gx] = (unsigned char)best;
    }
  } else {
    // ---------------- adaptive avg pool 126x126 -> 3x3 (42x42 blocks) ----------------
    int lin = blockIdx.x - 512;       // 4608
    int b = lin & 7;
    int rest = lin >> 3;              // 0..575
    int c = rest / 9, k = rest % 9;
    int kh = k / 3, kw = k % 3;
    const float* xp = x + ((size_t)(b * 64 + c) * 126 + kh * 42) * 126 + kw * 42;
    float s = 0.f;
    for (int i = t; i < 1764; i += 256)
      s += xp[(i / 42) * 126 + (i % 42)];
    #pragma unroll
    for (int off = 32; off; off >>= 1) s += __shfl_down(s, off);
    if ((t & 63) == 0) red[t >> 6] = s;
    __syncthreads();
    if (t == 0)
      pooled[(b * 64 + c) * 9 + k] = (red[0] + red[1] + red[2] + red[3]) * (1.f / 1764.f);
  }
}

// ---------------- K2: fused s1 + filter bank, 1152 blocks, b-swizzled ----------------
// F2 as uint4: idx = ((b*8+r)*72 + f)*64 + lane, f = kk*8 + slice*2 + cotile.
// Lane's 8 halves e: F(b,r, co=cotile*32+(lane&31), ci=slice*16+(lane>>5)*8+e, kk)
__global__ __launch_bounds__(256) void k_filt(const float* __restrict__ pooled,
                                              const float* __restrict__ w1,
                                              const float* __restrict__ b1,
                                              const float* __restrict__ w2,
                                              const float* __restrict__ b2,
                                              __half* __restrict__ F2) {
  int lin = blockIdx.x;             // 1152
  int b = lin & 7;
  int inner = lin >> 3;             // 0..143
  int r = inner / 18, jblk = inner % 18;
  int idx0 = (b * 8 + r) * 4608 + jblk * 256;
  __shared__ float s1l[8][9];       // [i][kk]
  int t = threadIdx.x;
  if (t < 72) {
    int i = t / 9, k = t - i * 9;
    int o = r * 8 + i;
    const float* pp = pooled + b * 576 + k;   // stride 9 per channel
    const float* wp = w1 + o * 64;
    float acc = b1[o];
    #pragma unroll 8
    for (int c = 0; c < 64; c++) acc += pp[c * 9] * wp[c];
    s1l[i][k] = 1.f / (1.f + expf(-acc));
  }
  __syncthreads();

  int idx = idx0 + t;
  int lane = idx & 63;
  int f = (idx >> 6) % 72;
  int cotile = f & 1, slice = (f >> 1) & 3, kk = f >> 3;
  int co = cotile * 32 + (lane & 31);
  int ci0 = slice * 16 + (lane >> 5) * 8;
  float sv[8];
  #pragma unroll
  for (int i = 0; i < 8; i++) sv[i] = s1l[i][kk];
  unsigned h[8];
  #pragma unroll
  for (int e = 0; e < 8; e++) {
    int o = co * 64 + (ci0 + e);
    float acc = b2[r * 4096 + o];
    const float* wp = w2 + (size_t)(r * 4096 + o) * 8;
    #pragma unroll
    for (int i = 0; i < 8; i++) acc += sv[i] * wp[i];
    h[e] = __half_as_ushort(__float2half(acc));
  }
  uint4 q;
  q.x = h[0] | (h[1] << 16);
  q.y = h[2] | (h[3] << 16);
  q.z = h[4] | (h[5] << 16);
  q.w = h[6] | (h[7] << 16);
  ((uint4*)F2)[idx] = q;
}

// ---------------- K3: MFMA region conv, 32x16 tiles, 1024 thr (16 waves) -------------
#define PATCH_U32S 19584    // 612 px * 32 ci-pairs
#define CBUF_OFF   78336    // u32[32][514] = 65,792 B
#define LIST_OFF   144128   // u16[8*512]   =  8,192 B
#define CNT_OFF    152320   // u32[8]
#define NG_OFF     152352   // u32[8] pair-counts
#define NGP_OFF    152384   // u32[8] prefix
#define WL_OFF     152416   // u8[40]
#define WLT_OFF    152456   // u32
#define SMEM3      152464

#define MFMA32(A, B, C) __builtin_amdgcn_mfma_f32_32x32x16_f16(A, B, C, 0, 0, 0)

#define LOADB(P, KK) { const uint4* fk = Fb + (KK) * 512;                    \
  P[0].q = fk[0];   P[1].q = fk[64];  P[2].q = fk[128]; P[3].q = fk[192];    \
  P[4].q = fk[256]; P[5].q = fk[320]; P[6].q = fk[384]; P[7].q = fk[448]; }

#define STEP(KK, B) {                                                        \
  int pxA = (prow0 + (KK) / 3) * 34 + pcol0 + (KK) % 3;                      \
  int pbA = pxA * 128, swA = (pxA & 7) << 4;                                 \
  half8 a0A = *(const half8*)(smem + pbA + ((0   + lhi * 16) ^ swA));        \
  half8 a1A = *(const half8*)(smem + pbA + ((32  + lhi * 16) ^ swA));        \
  half8 a2A = *(const half8*)(smem + pbA + ((64  + lhi * 16) ^ swA));        \
  half8 a3A = *(const half8*)(smem + pbA + ((96  + lhi * 16) ^ swA));        \
  int pxB = (prow1 + (KK) / 3) * 34 + pcol1 + (KK) % 3;                      \
  int pbB = pxB * 128, swB = (pxB & 7) << 4;                                 \
  half8 a0B = *(const half8*)(smem + pbB + ((0   + lhi * 16) ^ swB));        \
  half8 a1B = *(const half8*)(smem + pbB + ((32  + lhi * 16) ^ swB));        \
  half8 a2B = *(const half8*)(smem + pbB + ((64  + lhi * 16) ^ swB));        \
  half8 a3B = *(const half8*)(smem + pbB + ((96  + lhi * 16) ^ swB));        \
  __builtin_amdgcn_s_setprio(1);                                             \
  C00 = MFMA32(a0A, B[0].h, C00); C01 = MFMA32(a0A, B[1].h, C01);            \
  C10 = MFMA32(a0B, B[0].h, C10); C11 = MFMA32(a0B, B[1].h, C11);            \
  C00 = MFMA32(a1A, B[2].h, C00); C01 = MFMA32(a1A, B[3].h, C01);            \
  C10 = MFMA32(a1B, B[2].h, C10); C11 = MFMA32(a1B, B[3].h, C11);            \
  C00 = MFMA32(a2A, B[4].h, C00); C01 = MFMA32(a2A, B[5].h, C01);            \
  C10 = MFMA32(a2B, B[4].h, C10); C11 = MFMA32(a2B, B[5].h, C11);            \
  C00 = MFMA32(a3A, B[6].h, C00); C01 = MFMA32(a3A, B[7].h, C01);            \
  C10 = MFMA32(a3B, B[6].h, C10); C11 = MFMA32(a3B, B[7].h, C11);            \
  __builtin_amdgcn_s_setprio(0); }

__global__ __launch_bounds__(1024, 1) void k_conv3(const float* __restrict__ x,
                                                   const __half* __restrict__ F2,
                                                   const unsigned char* __restrict__ rmap,
                                                   float* __restrict__ out) {
  extern __shared__ __align__(16) char smem[];
  unsigned* cbuf = (unsigned*)(smem + CBUF_OFF);
  unsigned short* list = (unsigned short*)(smem + LIST_OFF);
  unsigned* cnt = (unsigned*)(smem + CNT_OFF);
  unsigned* ng = (unsigned*)(smem + NG_OFF);
  unsigned* ngp = (unsigned*)(smem + NGP_OFF);
  unsigned char* wl = (unsigned char*)(smem + WL_OFF);
  unsigned* wltot = (unsigned*)(smem + WLT_OFF);

  int lin = blockIdx.x;             // 256
  int b = lin & 7;
  int tile = lin >> 3;              // 0..31
  int tx = tile & 3, ty = tile >> 2;
  int x0 = tx * 32, y0 = ty * 16;
  int t = threadIdx.x;

  if (t < 8) cnt[t] = 0;

  // ---- hoist rmap load: issue before staging, consume after the barrier ----
  int myrow = t >> 5, mycol = t & 31;
  int mygy = y0 + myrow, mygx = x0 + mycol;
  bool myvalid = (t < 512) && (mygy < 124) && (mygx < 124);
  unsigned char rr_raw = 0;
  if (t < 512)
    rr_raw = rmap[b * NPIX + min(mygy, 123) * 124 + min(mygx, 123)];

  // ---- stage x patch: channel-last f16, XOR-swizzled, coalesced ----
  #pragma unroll 2
  for (int e = t; e < PATCH_U32S; e += 1024) {
    int ci2 = e / 612;
    int pix = e - ci2 * 612;
    int row = pix / 34, col = pix - row * 34;
    int gy = min(y0 + row, 125);
    int gx = min(x0 + col, 125);
    const float* xp = x + ((size_t)(b * 64 + ci2 * 2) * 126 + gy) * 126 + gx;
    PK pk; pk.h = __builtin_amdgcn_cvt_pkrtz(xp[0], xp[15876]);
    int byte = pix * 128 + ((ci2 * 4) ^ ((pix & 7) << 4));
    *(unsigned*)(smem + byte) = pk.u;
  }
  __syncthreads();   // patch staged, cnt zeroed

  // ---- per-region pixel lists (LDS atomics); px id = t for t < 512 ----
  if (myvalid) {
    unsigned pos = atomicAdd(&cnt[rr_raw], 1u);
    list[rr_raw * 512 + pos] = (unsigned short)t;
  }
  __syncthreads();

  // ---- worklist of (region, chunk-pair) units: parallel construction ----
  if (t < 8) {
    int nc = ((int)cnt[t] + 31) >> 5;    // 32-px chunks
    ng[t] = (unsigned)((nc + 1) >> 1);   // pairs
  }
  __syncthreads();
  if (t == 0) {
    unsigned tot = 0;
    #pragma unroll
    for (int r = 0; r < 8; r++) { ngp[r] = tot; tot += ng[r]; }
    *wltot = tot;
  }
  __syncthreads();
  if (t < 8) {
    unsigned base = ngp[t], n = ng[t];
    for (unsigned j = 0; j < n; j++) wl[base + j] = (unsigned char)((t << 4) | j);
  }
  __syncthreads();

  int wid = t >> 6;        // 0..15
  int lane = t & 63;
  int l31 = lane & 31, lhi = lane >> 5;
  int nunits = (int)*wltot;
  const uint4* F2q = (const uint4*)F2;

  for (int u = wid; u < nunits; u += 16) {
    int e = wl[u];
    int r = e >> 4, g = e & 15;
    int rcnt = (int)cnt[r];
    int s0 = g * 2, s1v = g * 2 + 1;
    int p0 = list[r * 512 + min(s0 * 32 + l31, rcnt - 1)];
    int p1 = list[r * 512 + min(s1v * 32 + l31, rcnt - 1)];
    int prow0 = p0 >> 5, pcol0 = p0 & 31;
    int prow1 = p1 >> 5, pcol1 = p1 & 31;
    const uint4* Fb = F2q + (size_t)(b * 8 + r) * 4608 + lane;

    f32x16 C00 = {0,0,0,0,0,0,0,0,0,0,0,0,0,0,0,0};
    f32x16 C01 = {0,0,0,0,0,0,0,0,0,0,0,0,0,0,0,0};
    f32x16 C10 = {0,0,0,0,0,0,0,0,0,0,0,0,0,0,0,0};
    f32x16 C11 = {0,0,0,0,0,0,0,0,0,0,0,0,0,0,0,0};

    Q2H bc[8], bn[8];

    LOADB(bc, 0);
    LOADB(bn, 1); STEP(0, bc);
    LOADB(bc, 2); STEP(1, bn);
    LOADB(bn, 3); STEP(2, bc);
    LOADB(bc, 4); STEP(3, bn);
    LOADB(bn, 5); STEP(4, bc);
    LOADB(bc, 6); STEP(5, bn);
    LOADB(bn, 7); STEP(6, bc);
    LOADB(bc, 8); STEP(7, bn);
    STEP(8, bc);

    // ---- pack (co, co+32) as f16x2 into cbuf (stride 514 -> conflict-free) ----
    #pragma unroll
    for (int reg = 0; reg < 16; reg++) {
      int row = (reg & 3) + 8 * (reg >> 2) + 4 * lhi;
      int si0 = s0 * 32 + row;
      if (si0 < rcnt) {
        int pp = list[r * 512 + si0];
        PK pk; pk.h = __builtin_amdgcn_cvt_pkrtz(C00[reg], C01[reg]);
        cbuf[l31 * 514 + pp] = pk.u;
      }
      int si1 = s1v * 32 + row;
      if (si1 < rcnt) {
        int pp = list[r * 512 + si1];
        PK pk; pk.h = __builtin_amdgcn_cvt_pkrtz(C10[reg], C11[reg]);
        cbuf[l31 * 514 + pp] = pk.u;
      }
    }
  }
  __syncthreads();   // all units done, cbuf complete

  // ---- final pass: coalesced dwordx2 stores, pixel pairs (8 cp per thread) ----
  {
    int cgrp = t >> 8;                // 0..3 -> cp = cgrp*8 + j
    int pe = (t & 255) * 2;           // even pixel index
    int prow = pe >> 5, pcol = pe & 31;
    int gy = y0 + prow, gx = x0 + pcol;
    if (gy < 124 && gx < 124) {       // gx even => gx+1 also valid
      float* ob = out + (size_t)b * 64 * NPIX + (size_t)gy * 124 + gx;
      #pragma unroll
      for (int j = 0; j < 8; j++) {
        int cp = cgrp * 8 + j;
        UPK c;
        c.q = *(const uint2*)&cbuf[cp * 514 + pe];
        float2 v0 = { (float)c.h[0], (float)c.h[2] };   // co=cp,    px pe, pe+1
        float2 v1 = { (float)c.h[1], (float)c.h[3] };   // co=cp+32, px pe, pe+1
        *(float2*)(ob + (size_t)cp * NPIX) = v0;
        *(float2*)(ob + (size_t)(cp + 32) * NPIX) = v1;
      }
    }
  }
}

extern "C" void kernel_launch(void* const* d_in, const int* in_sizes, int n_in,
                              void* d_out, int out_size, void* d_ws, size_t ws_size,
                              hipStream_t stream) {
  (void)in_sizes; (void)n_in; (void)out_size; (void)ws_size;
  const float* x  = (const float*)d_in[0];
  const float* w1 = (const float*)d_in[1];
  const float* b1 = (const float*)d_in[2];
  const float* w2 = (const float*)d_in[3];
  const float* b2 = (const float*)d_in[4];
  const float* wg = (const float*)d_in[5];
  const float* bg = (const float*)d_in[6];
  float* out = (float*)d_out;
  char* ws = (char*)d_ws;

  __half* F2          = (__half*)(ws);               // 4,718,592 B
  float* pooled       = (float*)(ws + 4718592);      //    18,432 B
  unsigned char* rmap = (unsigned char*)(ws + 4737024);  // 123,008 B

  (void)hipFuncSetAttribute((const void*)k_conv3,
                            hipFuncAttributeMaxDynamicSharedMemorySize, SMEM3);

  k_poolguide<<<5120, 256, 0, stream>>>(x, wg, bg, pooled, rmap);
  k_filt     <<<1152, 256, 0, stream>>>(pooled, w1, b1, w2, b2, F2);
  k_conv3    <<<256, 1024, SMEM3, stream>>>(x, F2, rmap, out);
}

// Round 18
// 72.493 us; speedup vs baseline: 1.5844x; 1.5844x over previous
//
#include <hip/hip_runtime.h>
#include <hip/hip_fp16.h>
#include <math.h>

#define NPIX 15376   // 124*124

typedef _Float16 half8 __attribute__((ext_vector_type(8)));
typedef __fp16 fp16x2 __attribute__((ext_vector_type(2)));
typedef float f32x16 __attribute__((ext_vector_type(16)));

union Q2H { uint4 q; half8 h; };
union PK  { fp16x2 h; unsigned u; };
union UPK { uint2 q; _Float16 h[4]; };

// b = lin & 7 on every kernel: HW round-robins linear block id across the 8 XCDs, so
// all blocks of batch b share one XCD's L2 (x[b]=4MB, F2[b]=0.59MB resident) and L2
// content chains across kernels.
// NOTE (R17 lesson): do NOT wrap the MFMA cluster in s_setprio here — the intrinsic
// forms a scheduling-region boundary inside the unrolled tap chain and spills the
// 16 in-flight B-fragment uint4s to scratch (WRITE_SIZE 33MB -> 209MB, +42us).

// ---------------- K1: fused pool + guide (heterogeneous blocks) ----------------------
__global__ __launch_bounds__(256) void k_poolguide(const float* __restrict__ x,
                                                   const float* __restrict__ wg,
                                                   const float* __restrict__ bg,
                                                   float* __restrict__ pooled,
                                                   unsigned char* __restrict__ rmap) {
  __shared__ float wgl[4608];   // guide: [ci][k][r]; pool uses only red[]
  __shared__ float red[4];
  int t = threadIdx.x;

  if (blockIdx.x < 512) {
    // ---------------- guide conv (f32) + argmax -> rmap, 1 px/thread ----------------
    // f32 accumulation order frozen (argmax exactness); unroll only issues loads
    // earlier, the fmaf sequence is unchanged.
    for (int i = t; i < 4608; i += 256) {
      int r = i / 576, rem = i % 576;      // rem = ci*9+k
      wgl[rem * 8 + r] = wg[i];
    }
    __syncthreads();
    int lin = blockIdx.x;             // 512
    int b = lin & 7;
    int tile = lin >> 3;              // 0..63
    int tx = tile & 7, ty = tile >> 3;
    int gx = tx * 16 + (t & 15);
    int gy = ty * 16 + (t >> 4);
    int xc = min(gx, 123);
    int yc = min(gy, 123);
    float a0[8];
    #pragma unroll
    for (int r = 0; r < 8; r++) a0[r] = bg[r];
    #pragma unroll 4
    for (int ci = 0; ci < 64; ci++) {
      const float* xp = x + ((size_t)(b * 64 + ci) * 126 + yc) * 126 + xc;
      const float4* wp4 = (const float4*)(wgl + ci * 72);
      #pragma unroll
      for (int k = 0; k < 9; k++) {
        float xv = xp[(k / 3) * 126 + (k % 3)];
        float4 wA = wp4[k * 2], wB = wp4[k * 2 + 1];
        a0[0] = fmaf(xv, wA.x, a0[0]); a0[1] = fmaf(xv, wA.y, a0[1]);
        a0[2] = fmaf(xv, wA.z, a0[2]); a0[3] = fmaf(xv, wA.w, a0[3]);
        a0[4] = fmaf(xv, wB.x, a0[4]); a0[5] = fmaf(xv, wB.y, a0[5]);
        a0[6] = fmaf(xv, wB.z, a0[6]); a0[7] = fmaf(xv, wB.w, a0[7]);
      }
    }
    if (gx < 124 && gy < 124) {
      int best = 0; float bv = a0[0];
      #pragma unroll
      for (int r = 1; r < 8; r++) if (a0[r] > bv) { bv = a0[r]; best = r; }
      rmap[b * NPIX + gy * 124 + gx] = (unsigned char)best;
    }
  } else {
    // ---------------- adaptive avg pool 126x126 -> 3x3 (42x42 blocks) ----------------
    int lin = blockIdx.x - 512;       // 4608
    int b = lin & 7;
    int rest = lin >> 3;              // 0..575
    int c = rest / 9, k = rest % 9;
    int kh = k / 3, kw = k % 3;
    const float* xp = x + ((size_t)(b * 64 + c) * 126 + kh * 42) * 126 + kw * 42;
    float s = 0.f;
    for (int i = t; i < 1764; i += 256)
      s += xp[(i / 42) * 126 + (i % 42)];
    #pragma unroll
    for (int off = 32; off; off >>= 1) s += __shfl_down(s, off);
    if ((t & 63) == 0) red[t >> 6] = s;
    __syncthreads();
    if (t == 0)
      pooled[(b * 64 + c) * 9 + k] = (red[0] + red[1] + red[2] + red[3]) * (1.f / 1764.f);
  }
}

// ---------------- K2: fused s1 + filter bank, 1152 blocks, b-swizzled ----------------
// F2 as uint4: idx = ((b*8+r)*72 + f)*64 + lane, f = kk*8 + slice*2 + cotile.
// Lane's 8 halves e: F(b,r, co=cotile*32+(lane&31), ci=slice*16+(lane>>5)*8+e, kk)
__global__ __launch_bounds__(256) void k_filt(const float* __restrict__ pooled,
                                              const float* __restrict__ w1,
                                              const float* __restrict__ b1,
                                              const float* __restrict__ w2,
                                              const float* __restrict__ b2,
                                              __half* __restrict__ F2) {
  int lin = blockIdx.x;             // 1152
  int b = lin & 7;
  int inner = lin >> 3;             // 0..143
  int r = inner / 18, jblk = inner % 18;
  int idx0 = (b * 8 + r) * 4608 + jblk * 256;
  __shared__ float s1l[8][9];       // [i][kk]
  int t = threadIdx.x;
  if (t < 72) {
    int i = t / 9, k = t - i * 9;
    int o = r * 8 + i;
    const float* pp = pooled + b * 576 + k;   // stride 9 per channel
    const float* wp = w1 + o * 64;
    float acc = b1[o];
    #pragma unroll 8
    for (int c = 0; c < 64; c++) acc += pp[c * 9] * wp[c];
    s1l[i][k] = 1.f / (1.f + expf(-acc));
  }
  __syncthreads();

  int idx = idx0 + t;
  int lane = idx & 63;
  int f = (idx >> 6) % 72;
  int cotile = f & 1, slice = (f >> 1) & 3, kk = f >> 3;
  int co = cotile * 32 + (lane & 31);
  int ci0 = slice * 16 + (lane >> 5) * 8;
  float sv[8];
  #pragma unroll
  for (int i = 0; i < 8; i++) sv[i] = s1l[i][kk];
  unsigned h[8];
  #pragma unroll
  for (int e = 0; e < 8; e++) {
    int o = co * 64 + (ci0 + e);
    float acc = b2[r * 4096 + o];
    const float* wp = w2 + (size_t)(r * 4096 + o) * 8;
    #pragma unroll
    for (int i = 0; i < 8; i++) acc += sv[i] * wp[i];
    h[e] = __half_as_ushort(__float2half(acc));
  }
  uint4 q;
  q.x = h[0] | (h[1] << 16);
  q.y = h[2] | (h[3] << 16);
  q.z = h[4] | (h[5] << 16);
  q.w = h[6] | (h[7] << 16);
  ((uint4*)F2)[idx] = q;
}

// ---------------- K3: MFMA region conv, 32x16 tiles, 1024 thr (16 waves) -------------
#define PATCH_U32S 19584    // 612 px * 32 ci-pairs
#define CBUF_OFF   78336    // u32[32][514] = 65,792 B
#define LIST_OFF   144128   // u16[8*512]   =  8,192 B
#define CNT_OFF    152320   // u32[8]
#define NG_OFF     152352   // u32[8] pair-counts
#define NGP_OFF    152384   // u32[8] prefix
#define WL_OFF     152416   // u8[40]
#define WLT_OFF    152456   // u32
#define SMEM3      152464

#define MFMA32(A, B, C) __builtin_amdgcn_mfma_f32_32x32x16_f16(A, B, C, 0, 0, 0)

#define LOADB(P, KK) { const uint4* fk = Fb + (KK) * 512;                    \
  P[0].q = fk[0];   P[1].q = fk[64];  P[2].q = fk[128]; P[3].q = fk[192];    \
  P[4].q = fk[256]; P[5].q = fk[320]; P[6].q = fk[384]; P[7].q = fk[448]; }

#define STEP(KK, B) {                                                        \
  int pxA = (prow0 + (KK) / 3) * 34 + pcol0 + (KK) % 3;                      \
  int pbA = pxA * 128, swA = (pxA & 7) << 4;                                 \
  half8 a0A = *(const half8*)(smem + pbA + ((0   + lhi * 16) ^ swA));        \
  half8 a1A = *(const half8*)(smem + pbA + ((32  + lhi * 16) ^ swA));        \
  half8 a2A = *(const half8*)(smem + pbA + ((64  + lhi * 16) ^ swA));        \
  half8 a3A = *(const half8*)(smem + pbA + ((96  + lhi * 16) ^ swA));        \
  int pxB = (prow1 + (KK) / 3) * 34 + pcol1 + (KK) % 3;                      \
  int pbB = pxB * 128, swB = (pxB & 7) << 4;                                 \
  half8 a0B = *(const half8*)(smem + pbB + ((0   + lhi * 16) ^ swB));        \
  half8 a1B = *(const half8*)(smem + pbB + ((32  + lhi * 16) ^ swB));        \
  half8 a2B = *(const half8*)(smem + pbB + ((64  + lhi * 16) ^ swB));        \
  half8 a3B = *(const half8*)(smem + pbB + ((96  + lhi * 16) ^ swB));        \
  C00 = MFMA32(a0A, B[0].h, C00); C01 = MFMA32(a0A, B[1].h, C01);            \
  C10 = MFMA32(a0B, B[0].h, C10); C11 = MFMA32(a0B, B[1].h, C11);            \
  C00 = MFMA32(a1A, B[2].h, C00); C01 = MFMA32(a1A, B[3].h, C01);            \
  C10 = MFMA32(a1B, B[2].h, C10); C11 = MFMA32(a1B, B[3].h, C11);            \
  C00 = MFMA32(a2A, B[4].h, C00); C01 = MFMA32(a2A, B[5].h, C01);            \
  C10 = MFMA32(a2B, B[4].h, C10); C11 = MFMA32(a2B, B[5].h, C11);            \
  C00 = MFMA32(a3A, B[6].h, C00); C01 = MFMA32(a3A, B[7].h, C01);            \
  C10 = MFMA32(a3B, B[6].h, C10); C11 = MFMA32(a3B, B[7].h, C11); }

__global__ __launch_bounds__(1024, 1) void k_conv3(const float* __restrict__ x,
                                                   const __half* __restrict__ F2,
                                                   const unsigned char* __restrict__ rmap,
                                                   float* __restrict__ out) {
  extern __shared__ __align__(16) char smem[];
  unsigned* cbuf = (unsigned*)(smem + CBUF_OFF);
  unsigned short* list = (unsigned short*)(smem + LIST_OFF);
  unsigned* cnt = (unsigned*)(smem + CNT_OFF);
  unsigned* ng = (unsigned*)(smem + NG_OFF);
  unsigned* ngp = (unsigned*)(smem + NGP_OFF);
  unsigned char* wl = (unsigned char*)(smem + WL_OFF);
  unsigned* wltot = (unsigned*)(smem + WLT_OFF);

  int lin = blockIdx.x;             // 256
  int b = lin & 7;
  int tile = lin >> 3;              // 0..31
  int tx = tile & 3, ty = tile >> 2;
  int x0 = tx * 32, y0 = ty * 16;
  int t = threadIdx.x;

  if (t < 8) cnt[t] = 0;

  // ---- hoist rmap load: issue before staging, consume after the barrier ----
  int myrow = t >> 5, mycol = t & 31;
  int mygy = y0 + myrow, mygx = x0 + mycol;
  bool myvalid = (t < 512) && (mygy < 124) && (mygx < 124);
  unsigned char rr_raw = 0;
  if (t < 512)
    rr_raw = rmap[b * NPIX + min(mygy, 123) * 124 + min(mygx, 123)];

  // ---- stage x patch: channel-last f16, XOR-swizzled, coalesced ----
  #pragma unroll 2
  for (int e = t; e < PATCH_U32S; e += 1024) {
    int ci2 = e / 612;
    int pix = e - ci2 * 612;
    int row = pix / 34, col = pix - row * 34;
    int gy = min(y0 + row, 125);
    int gx = min(x0 + col, 125);
    const float* xp = x + ((size_t)(b * 64 + ci2 * 2) * 126 + gy) * 126 + gx;
    PK pk; pk.h = __builtin_amdgcn_cvt_pkrtz(xp[0], xp[15876]);
    int byte = pix * 128 + ((ci2 * 4) ^ ((pix & 7) << 4));
    *(unsigned*)(smem + byte) = pk.u;
  }
  __syncthreads();   // patch staged, cnt zeroed

  // ---- per-region pixel lists (LDS atomics); px id = t for t < 512 ----
  if (myvalid) {
    unsigned pos = atomicAdd(&cnt[rr_raw], 1u);
    list[rr_raw * 512 + pos] = (unsigned short)t;
  }
  __syncthreads();

  // ---- worklist of (region, chunk-pair) units: parallel construction ----
  if (t < 8) {
    int nc = ((int)cnt[t] + 31) >> 5;    // 32-px chunks
    ng[t] = (unsigned)((nc + 1) >> 1);   // pairs
  }
  __syncthreads();
  if (t == 0) {
    unsigned tot = 0;
    #pragma unroll
    for (int r = 0; r < 8; r++) { ngp[r] = tot; tot += ng[r]; }
    *wltot = tot;
  }
  __syncthreads();
  if (t < 8) {
    unsigned base = ngp[t], n = ng[t];
    for (unsigned j = 0; j < n; j++) wl[base + j] = (unsigned char)((t << 4) | j);
  }
  __syncthreads();

  int wid = t >> 6;        // 0..15
  int lane = t & 63;
  int l31 = lane & 31, lhi = lane >> 5;
  int nunits = (int)*wltot;
  const uint4* F2q = (const uint4*)F2;

  for (int u = wid; u < nunits; u += 16) {
    int e = wl[u];
    int r = e >> 4, g = e & 15;
    int rcnt = (int)cnt[r];
    int s0 = g * 2, s1v = g * 2 + 1;
    int p0 = list[r * 512 + min(s0 * 32 + l31, rcnt - 1)];
    int p1 = list[r * 512 + min(s1v * 32 + l31, rcnt - 1)];
    int prow0 = p0 >> 5, pcol0 = p0 & 31;
    int prow1 = p1 >> 5, pcol1 = p1 & 31;
    const uint4* Fb = F2q + (size_t)(b * 8 + r) * 4608 + lane;

    f32x16 C00 = {0,0,0,0,0,0,0,0,0,0,0,0,0,0,0,0};
    f32x16 C01 = {0,0,0,0,0,0,0,0,0,0,0,0,0,0,0,0};
    f32x16 C10 = {0,0,0,0,0,0,0,0,0,0,0,0,0,0,0,0};
    f32x16 C11 = {0,0,0,0,0,0,0,0,0,0,0,0,0,0,0,0};

    Q2H bc[8], bn[8];

    LOADB(bc, 0);
    LOADB(bn, 1); STEP(0, bc);
    LOADB(bc, 2); STEP(1, bn);
    LOADB(bn, 3); STEP(2, bc);
    LOADB(bc, 4); STEP(3, bn);
    LOADB(bn, 5); STEP(4, bc);
    LOADB(bc, 6); STEP(5, bn);
    LOADB(bn, 7); STEP(6, bc);
    LOADB(bc, 8); STEP(7, bn);
    STEP(8, bc);

    // ---- pack (co, co+32) as f16x2 into cbuf (stride 514 -> conflict-free) ----
    #pragma unroll
    for (int reg = 0; reg < 16; reg++) {
      int row = (reg & 3) + 8 * (reg >> 2) + 4 * lhi;
      int si0 = s0 * 32 + row;
      if (si0 < rcnt) {
        int pp = list[r * 512 + si0];
        PK pk; pk.h = __builtin_amdgcn_cvt_pkrtz(C00[reg], C01[reg]);
        cbuf[l31 * 514 + pp] = pk.u;
      }
      int si1 = s1v * 32 + row;
      if (si1 < rcnt) {
        int pp = list[r * 512 + si1];
        PK pk; pk.h = __builtin_amdgcn_cvt_pkrtz(C10[reg], C11[reg]);
        cbuf[l31 * 514 + pp] = pk.u;
      }
    }
  }
  __syncthreads();   // all units done, cbuf complete

  // ---- final pass: coalesced dwordx2 stores, pixel pairs (8 cp per thread) ----
  {
    int cgrp = t >> 8;                // 0..3 -> cp = cgrp*8 + j
    int pe = (t & 255) * 2;           // even pixel index
    int prow = pe >> 5, pcol = pe & 31;
    int gy = y0 + prow, gx = x0 + pcol;
    if (gy < 124 && gx < 124) {       // gx even => gx+1 also valid
      float* ob = out + (size_t)b * 64 * NPIX + (size_t)gy * 124 + gx;
      #pragma unroll
      for (int j = 0; j < 8; j++) {
        int cp = cgrp * 8 + j;
        UPK c;
        c.q = *(const uint2*)&cbuf[cp * 514 + pe];
        float2 v0 = { (float)c.h[0], (float)c.h[2] };   // co=cp,    px pe, pe+1
        float2 v1 = { (float)c.h[1], (float)c.h[3] };   // co=cp+32, px pe, pe+1
        *(float2*)(ob + (size_t)cp * NPIX) = v0;
        *(float2*)(ob + (size_t)(cp + 32) * NPIX) = v1;
      }
    }
  }
}

extern "C" void kernel_launch(void* const* d_in, const int* in_sizes, int n_in,
                              void* d_out, int out_size, void* d_ws, size_t ws_size,
                              hipStream_t stream) {
  (void)in_sizes; (void)n_in; (void)out_size; (void)ws_size;
  const float* x  = (const float*)d_in[0];
  const float* w1 = (const float*)d_in[1];
  const float* b1 = (const float*)d_in[2];
  const float* w2 = (const float*)d_in[3];
  const float* b2 = (const float*)d_in[4];
  const float* wg = (const float*)d_in[5];
  const float* bg = (const float*)d_in[6];
  float* out = (float*)d_out;
  char* ws = (char*)d_ws;

  __half* F2          = (__half*)(ws);               // 4,718,592 B
  float* pooled       = (float*)(ws + 4718592);      //    18,432 B
  unsigned char* rmap = (unsigned char*)(ws + 4737024);  // 123,008 B

  (void)hipFuncSetAttribute((const void*)k_conv3,
                            hipFuncAttributeMaxDynamicSharedMemorySize, SMEM3);

  k_poolguide<<<5120, 256, 0, stream>>>(x, wg, bg, pooled, rmap);
  k_filt     <<<1152, 256, 0, stream>>>(pooled, w1, b1, w2, b2, F2);
  k_conv3    <<<256, 1024, SMEM3, stream>>>(x, F2, rmap, out);
}